// Round 2
// baseline (2373.447 us; speedup 1.0000x reference)
//
#include <hip/hip_runtime.h>
#include <hip/hip_bf16.h>

typedef __attribute__((ext_vector_type(8))) short bf16x8;
typedef __attribute__((ext_vector_type(4))) float f32x4;
typedef __hip_bfloat16 bf16;

// ---------------------------------------------------------------------------
// transpose + fp32 -> bf16 convert:  in [batch][R][Cc] -> out [batch][Cc][R]
// ---------------------------------------------------------------------------
__global__ __launch_bounds__(256) void transpose_cvt(
    const float* __restrict__ in, bf16* __restrict__ out, int R, int Cc)
{
  __shared__ float tile[32][33];
  long base = (long)blockIdx.z * R * Cc;
  int c0 = blockIdx.x * 32, r0 = blockIdx.y * 32;
  int tx = threadIdx.x & 31, ty = threadIdx.x >> 5;   // 256 thr: ty 0..7
  #pragma unroll
  for (int i = 0; i < 32; i += 8)
    tile[ty + i][tx] = in[base + (long)(r0 + ty + i) * Cc + (c0 + tx)];
  __syncthreads();
  #pragma unroll
  for (int i = 0; i < 32; i += 8)
    out[base + (long)(c0 + ty + i) * R + (r0 + tx)] =
        __float2bfloat16(tile[tx][ty + i]);
}

// ---------------------------------------------------------------------------
// h = x + pos_emb  (pos broadcast over batch; T*C = 2^20)
// ---------------------------------------------------------------------------
__global__ __launch_bounds__(256) void add_pos(
    const float* __restrict__ x, const float* __restrict__ pos,
    float* __restrict__ h)
{
  int i = blockIdx.x * 1024 + threadIdx.x;
  #pragma unroll
  for (int j = 0; j < 4; ++j) {
    int idx = i + j * 256;
    h[idx] = x[idx] + pos[idx & ((1 << 20) - 1)];
  }
}

__device__ inline float wave_sum(float v) {
  #pragma unroll
  for (int o = 32; o; o >>= 1) v += __shfl_down(v, o, 64);
  return v;
}

// ---------------------------------------------------------------------------
// LayerNorm over rows of 1024; out bf16 (intermediate) or f32 (final)
// ---------------------------------------------------------------------------
template<bool F32OUT>
__global__ __launch_bounds__(256) void layernorm_k(
    const float* __restrict__ x, const float* __restrict__ s,
    const float* __restrict__ b, void* __restrict__ outv)
{
  __shared__ float red[8];
  long row = blockIdx.x;
  const float* xr = x + (row << 10);
  int t = threadIdx.x;
  float v[4]; float sum = 0.f, sq = 0.f;
  #pragma unroll
  for (int i = 0; i < 4; ++i) {
    v[i] = xr[t + i * 256];
    sum += v[i]; sq += v[i] * v[i];
  }
  sum = wave_sum(sum); sq = wave_sum(sq);
  if ((t & 63) == 0) { red[t >> 6] = sum; red[4 + (t >> 6)] = sq; }
  __syncthreads();
  sum = red[0] + red[1] + red[2] + red[3];
  sq  = red[4] + red[5] + red[6] + red[7];
  float mean = sum * (1.f / 1024.f);
  float var  = sq * (1.f / 1024.f) - mean * mean;
  float rstd = rsqrtf(var + 1e-5f);
  #pragma unroll
  for (int i = 0; i < 4; ++i) {
    int c = t + i * 256;
    float y = (v[i] - mean) * rstd * s[c] + b[c];
    if (F32OUT) ((float*)outv)[(row << 10) + c] = y;
    else        ((bf16*)outv)[(row << 10) + c] = __float2bfloat16(y);
  }
}

// ---------------------------------------------------------------------------
// softmax over rows of 1024, in place on d_out (fp32), plus bf16 copy in ws
// reordered from per-layer (h,b,t) row order to (b,h,t) for the att@v GEMM.
// ---------------------------------------------------------------------------
__global__ __launch_bounds__(256) void softmax_attn(
    float* __restrict__ att, bf16* __restrict__ attb)
{
  __shared__ float red[8];
  long r = blockIdx.x;
  float* ar = att + (r << 10);
  int t = threadIdx.x;
  float v[4]; float mx = -3.4e38f;
  #pragma unroll
  for (int i = 0; i < 4; ++i) { v[i] = ar[t + i * 256]; mx = fmaxf(mx, v[i]); }
  #pragma unroll
  for (int o = 32; o; o >>= 1) mx = fmaxf(mx, __shfl_down(mx, o, 64));
  if ((t & 63) == 0) red[t >> 6] = mx;
  __syncthreads();
  mx = fmaxf(fmaxf(red[0], red[1]), fmaxf(red[2], red[3]));
  float sum = 0.f;
  #pragma unroll
  for (int i = 0; i < 4; ++i) { v[i] = __expf(v[i] - mx); sum += v[i]; }
  sum = wave_sum(sum);
  if ((t & 63) == 0) red[4 + (t >> 6)] = sum;
  __syncthreads();
  sum = red[4] + red[5] + red[6] + red[7];
  float inv = 1.f / sum;
  int hh = (int)(r >> 12) & 7;          // layer-local rows: [h][b][t]
  int bb = (int)(r >> 10) & 3;
  long tt = r & 1023;
  bf16* abr = attb + ((((long)(bb * 8 + hh) << 10) + tt) << 10);
  #pragma unroll
  for (int i = 0; i < 4; ++i) {
    float p = v[i] * inv;
    ar[t + i * 256]  = p;
    abr[t + i * 256] = __float2bfloat16(p);
  }
}

// ---------------------------------------------------------------------------
// Generic bf16 GEMM, C = A[M,K] * Bt[N,K]^T, 128x128 tile, BK=64, 4 waves,
// 4x4 x mfma_f32_16x16x32_bf16 per wave, global_load_lds 16B staging (m97).
// Epilogue variants via template.
// ---------------------------------------------------------------------------
enum { EPI_BHTD = 0, EPI_VT, EPI_SCORES, EPI_ATTV, EPI_RES, EPI_RELU };

template<int EPI>
__global__ __launch_bounds__(256, 2) void gemm_bt(
    const bf16* __restrict__ A, const bf16* __restrict__ Bt,
    void* __restrict__ Cout, const float* __restrict__ bias, float scale,
    int M, int N, int K, int lda, int ldb, long sAb, long sBb)
{
  __shared__ __align__(16) bf16 sA[128 * 64];
  __shared__ __align__(16) bf16 sB[128 * 64];
  const int tid = threadIdx.x;
  const int bn = blockIdx.x, bm = blockIdx.y, bz = blockIdx.z;
  const bf16* Ab = A + bz * sAb + (long)bm * 128 * lda;
  const bf16* Bb = Bt + bz * sBb + (long)bn * 128 * ldb;
  const int wave = tid >> 6, lane = tid & 63;
  const int wm = (wave >> 1) * 64, wn = (wave & 1) * 64;
  const int quad = lane >> 4, l16 = lane & 15;

  f32x4 acc[4][4] = {};

  for (int k0 = 0; k0 < K; k0 += 64) {
    // stage 128x64 bf16 tile = 16 KB = 1024 chunks of 16B -> 4 iters x 256 thr
    #pragma unroll
    for (int i = 0; i < 4; ++i) {
      int c = i * 256 + tid;                 // 16B chunk id, 0..1023
      int row = c >> 3, col = (c & 7) << 3;  // [128 rows][64 cols]
      int ldsoff = (i * 256 + (tid & ~63)) << 3;  // wave-uniform base (elems)
      __builtin_amdgcn_global_load_lds(
          (const __attribute__((address_space(1))) void*)(Ab + (long)row * lda + (k0 + col)),
          (__attribute__((address_space(3))) void*)(sA + ldsoff), 16, 0, 0);
      __builtin_amdgcn_global_load_lds(
          (const __attribute__((address_space(1))) void*)(Bb + (long)row * ldb + (k0 + col)),
          (__attribute__((address_space(3))) void*)(sB + ldsoff), 16, 0, 0);
    }
    __syncthreads();
    #pragma unroll
    for (int kk = 0; kk < 64; kk += 32) {
      bf16x8 af[4], bfr[4];
      #pragma unroll
      for (int i = 0; i < 4; ++i) {
        af[i]  = *(const bf16x8*)(sA + (wm + i * 16 + l16) * 64 + kk + quad * 8);
        bfr[i] = *(const bf16x8*)(sB + (wn + i * 16 + l16) * 64 + kk + quad * 8);
      }
      #pragma unroll
      for (int i = 0; i < 4; ++i)
        #pragma unroll
        for (int j = 0; j < 4; ++j)
          acc[i][j] = __builtin_amdgcn_mfma_f32_16x16x32_bf16(
              af[i], bfr[j], acc[i][j], 0, 0, 0);
    }
    __syncthreads();
  }

  #pragma unroll
  for (int i = 0; i < 4; ++i) {
    #pragma unroll
    for (int j = 0; j < 4; ++j) {
      #pragma unroll
      for (int r = 0; r < 4; ++r) {
        int m = (bm << 7) + wm + i * 16 + (quad << 2) + r;
        int n = (bn << 7) + wn + j * 16 + l16;
        float v = acc[i][j][r];
        if (EPI == EPI_BHTD) {
          // q/k: [B,H,T,D]; m=(b,t), n=(h,d); T*D = 2^17
          long idx = ((long)((m >> 10) * 8 + (n >> 7)) << 17) +
                     ((long)(m & 1023) << 7) + (n & 127);
          ((bf16*)Cout)[idx] = __float2bfloat16(v);
        } else if (EPI == EPI_VT) {
          // vT: [B,H,D,T]
          long idx = ((long)((m >> 10) * 8 + (n >> 7)) << 17) +
                     ((long)(n & 127) << 10) + (m & 1023);
          ((bf16*)Cout)[idx] = __float2bfloat16(v);
        } else if (EPI == EPI_SCORES) {
          // batch bz=(b*8+h); out att layer base, order [h][b][t][s]
          long idx = ((long)((bz & 7) * 4 + (bz >> 3)) << 20) +
                     ((long)m << 10) + n;
          ((float*)Cout)[idx] = v * scale;
        } else if (EPI == EPI_ATTV) {
          // o: [B,T,C]; bz = b*8+h; m=t, n=d
          long idx = ((long)(bz >> 3) << 20) + ((long)m << 10) +
                     ((bz & 7) << 7) + n;
          ((bf16*)Cout)[idx] = __float2bfloat16(v);
        } else if (EPI == EPI_RES) {
          long idx = (long)m * N + n;
          ((float*)Cout)[idx] += v + bias[n];
        } else { // EPI_RELU
          long idx = (long)m * N + n;
          ((bf16*)Cout)[idx] = __float2bfloat16(fmaxf(v + bias[n], 0.f));
        }
      }
    }
  }
}

// ---------------------------------------------------------------------------
extern "C" void kernel_launch(void* const* d_in, const int* in_sizes, int n_in,
                              void* d_out, int out_size, void* d_ws, size_t ws_size,
                              hipStream_t stream)
{
  const float* x     = (const float*)d_in[0];
  const float* pos   = (const float*)d_in[1];
  const float* Wq    = (const float*)d_in[2];
  const float* Wk    = (const float*)d_in[3];
  const float* Wv    = (const float*)d_in[4];
  const float* Wo    = (const float*)d_in[5];
  const float* bo    = (const float*)d_in[6];
  const float* ln1_s = (const float*)d_in[7];
  const float* ln1_b = (const float*)d_in[8];
  const float* ln2_s = (const float*)d_in[9];
  const float* ln2_b = (const float*)d_in[10];
  const float* W1    = (const float*)d_in[11];
  const float* b1    = (const float*)d_in[12];
  const float* W2    = (const float*)d_in[13];
  const float* b2    = (const float*)d_in[14];
  const float* lnf_s = (const float*)d_in[15];
  const float* lnf_b = (const float*)d_in[16];
  float* out = (float*)d_out;

  char* w = (char*)d_ws;
  float* h  = (float*)w;                       // 16 MB  residual stream fp32
  bf16* xn  = (bf16*)(w + (16l  << 20));       //  8 MB  LN output bf16
  bf16* q   = (bf16*)(w + (24l  << 20));       //  8 MB  [B,H,T,D]
  bf16* kb  = (bf16*)(w + (32l  << 20));       //  8 MB  [B,H,T,D]
  bf16* vT  = (bf16*)(w + (40l  << 20));       //  8 MB  [B,H,D,T]
  bf16* o   = (bf16*)(w + (48l  << 20));       //  8 MB  [B,T,C]
  bf16* big = (bf16*)(w + (56l  << 20));       // 64 MB  attb (b,h,T,T) / hbuf
  bf16* WqT = (bf16*)(w + (120l << 20));       //  8 MB  [L,H*D,C]
  bf16* WkT = (bf16*)(w + (128l << 20));
  bf16* WvT = (bf16*)(w + (136l << 20));
  bf16* WoT = (bf16*)(w + (144l << 20));       //  8 MB  [L,C,C]
  bf16* W1T = (bf16*)(w + (152l << 20));       // 32 MB  [L,F,C]
  bf16* W2T = (bf16*)(w + (184l << 20));       // 32 MB  [L,C,F]  (ends 216MB)

  dim3 blk(256);
  transpose_cvt<<<dim3(4, 32, 32),  blk, 0, stream>>>(Wq, WqT, 1024, 128);
  transpose_cvt<<<dim3(4, 32, 32),  blk, 0, stream>>>(Wk, WkT, 1024, 128);
  transpose_cvt<<<dim3(4, 32, 32),  blk, 0, stream>>>(Wv, WvT, 1024, 128);
  transpose_cvt<<<dim3(32, 32, 4),  blk, 0, stream>>>(Wo, WoT, 1024, 1024);
  transpose_cvt<<<dim3(128, 32, 4), blk, 0, stream>>>(W1, W1T, 1024, 4096);
  transpose_cvt<<<dim3(32, 128, 4), blk, 0, stream>>>(W2, W2T, 4096, 1024);

  add_pos<<<4096, blk, 0, stream>>>(x, pos, h);

  const float scale = 0.08838834764831845f;   // 1/sqrt(128)
  for (int l = 0; l < 4; ++l) {
    layernorm_k<false><<<4096, blk, 0, stream>>>(h, ln1_s + l * 1024, ln1_b + l * 1024, xn);
    gemm_bt<EPI_BHTD><<<dim3(8, 32, 1), blk, 0, stream>>>(
        xn, WqT + (long)l * 1048576, q, nullptr, 0.f, 4096, 1024, 1024, 1024, 1024, 0, 0);
    gemm_bt<EPI_BHTD><<<dim3(8, 32, 1), blk, 0, stream>>>(
        xn, WkT + (long)l * 1048576, kb, nullptr, 0.f, 4096, 1024, 1024, 1024, 1024, 0, 0);
    gemm_bt<EPI_VT><<<dim3(8, 32, 1), blk, 0, stream>>>(
        xn, WvT + (long)l * 1048576, vT, nullptr, 0.f, 4096, 1024, 1024, 1024, 1024, 0, 0);

    float* attL = out + 4194304l + (long)l * 33554432l;  // atts[l] base
    gemm_bt<EPI_SCORES><<<dim3(8, 8, 32), blk, 0, stream>>>(
        q, kb, attL, nullptr, scale, 1024, 1024, 128, 128, 128, 131072l, 131072l);
    softmax_attn<<<32768, blk, 0, stream>>>(attL, big);
    gemm_bt<EPI_ATTV><<<dim3(1, 8, 32), blk, 0, stream>>>(
        big, vT, o, nullptr, 0.f, 1024, 128, 1024, 1024, 1024, 1048576l, 131072l);
    gemm_bt<EPI_RES><<<dim3(8, 32, 1), blk, 0, stream>>>(
        o, WoT + (long)l * 1048576, h, bo + l * 1024, 0.f, 4096, 1024, 1024, 1024, 1024, 0, 0);

    layernorm_k<false><<<4096, blk, 0, stream>>>(h, ln2_s + l * 1024, ln2_b + l * 1024, xn);
    gemm_bt<EPI_RELU><<<dim3(32, 32, 1), blk, 0, stream>>>(
        xn, W1T + (long)l * 4194304, big, b1 + l * 4096, 0.f, 4096, 4096, 1024, 1024, 1024, 0, 0);
    gemm_bt<EPI_RES><<<dim3(8, 32, 1), blk, 0, stream>>>(
        big, W2T + (long)l * 4194304, h, b2 + l * 1024, 0.f, 4096, 1024, 4096, 4096, 4096, 0, 0);
  }
  layernorm_k<true><<<4096, blk, 0, stream>>>(h, lnf_s, lnf_b, out);
}